// Round 7
// baseline (211.276 us; speedup 1.0000x reference)
//
#include <hip/hip_runtime.h>

#define NB    4096      // histogram buckets over [0,1)
#define CAP   4096      // per-batch candidate capacity (expected ~64 in threshold bucket)
#define BATCH 32
#define NTOK  262144    // 512*512
#define HPB   8         // fused blocks per batch
#define ABLK  (BATCH * HPB)   // 256
#define ATHR  1024

typedef float f4 __attribute__((ext_vector_type(4)));

__device__ __forceinline__ int bucket_of(float v) {
    int b = (int)(v * (float)NB);
    return b > NB - 1 ? NB - 1 : b;
}

// dd = logp0 - logp1 (incl gumbel), bce = -logp1 (clamped).
// loss = sum_all(bce) - sum_selected(dd)  [exact: -logp0 == -logp1 - dd]
__device__ __forceinline__ void token_terms(float d0, float d1, float u0, float u1,
                                            float& dd, float& bce) {
    float g0 = -__logf(-__logf(u0));
    float g1 = -__logf(-__logf(u1));
    dd = (d0 + g0) - (d1 + g1);
    float l = __logf(1.f + __expf(-fabsf(dd)));   // softplus(-|dd|)
    bce = fminf(l + fmaxf(dd, 0.f), 100.f);       // -logp1, clamp mirrors torch -100
}

// --- Pass A (R4-proven, 56.4us): ONE sweep of ds,u,smap -> per-block partial
// histogram (u16), per-bucket dd-sums (f32), BCE partial. 160MB = every input
// byte read exactly once (algorithmic minimum). 256 blocks x 1024 thr.
__global__ __launch_bounds__(1024) void fused_kernel(
        const float* __restrict__ ds, const float* __restrict__ u,
        const float* __restrict__ smap,
        unsigned short* __restrict__ hist_part, float* __restrict__ dsum_part,
        float* __restrict__ bce_part) {
    __shared__ int   lh[NB];     // 16 KB counts
    __shared__ float ldd[NB];    // 16 KB dd sums
    for (int i = threadIdx.x; i < NB; i += ATHR) { lh[i] = 0; ldd[i] = 0.f; }
    __syncthreads();
    const int b  = blockIdx.x >> 3;
    const int cb = blockIdx.x & 7;
    const size_t Q0 = (size_t)b * (NTOK / 4) + (size_t)cb * (NTOK / 4 / HPB); // quad idx
    const f4* s4 = (const f4*)smap + Q0;
    const f4* d4 = (const f4*)ds + 2 * Q0;
    const f4* u4 = (const f4*)u  + 2 * Q0;
    float bce = 0.f;
    for (int k = 0; k < 8; k++) {
        int q = threadIdx.x + k * ATHR;            // 0..8191 quad within block
        f4 sv = s4[q];                             // cached (reused by collect)
        f4 dA = __builtin_nontemporal_load(&d4[2 * q]);
        f4 dB = __builtin_nontemporal_load(&d4[2 * q + 1]);
        f4 uA = __builtin_nontemporal_load(&u4[2 * q]);
        f4 uB = __builtin_nontemporal_load(&u4[2 * q + 1]);
        float dd0, dd1, dd2, dd3, t0, t1, t2, t3;
        token_terms(dA.x, dA.y, uA.x, uA.y, dd0, t0);
        token_terms(dA.z, dA.w, uA.z, uA.w, dd1, t1);
        token_terms(dB.x, dB.y, uB.x, uB.y, dd2, t2);
        token_terms(dB.z, dB.w, uB.z, uB.w, dd3, t3);
        bce += (t0 + t1) + (t2 + t3);
        atomicAdd(&lh[bucket_of(sv.x)], 1); atomicAdd(&ldd[bucket_of(sv.x)], dd0);
        atomicAdd(&lh[bucket_of(sv.y)], 1); atomicAdd(&ldd[bucket_of(sv.y)], dd1);
        atomicAdd(&lh[bucket_of(sv.z)], 1); atomicAdd(&ldd[bucket_of(sv.z)], dd2);
        atomicAdd(&lh[bucket_of(sv.w)], 1); atomicAdd(&ldd[bucket_of(sv.w)], dd3);
    }
    __syncthreads();
    unsigned short* hp = hist_part + (size_t)blockIdx.x * NB;
    float*          dp = dsum_part + (size_t)blockIdx.x * NB;
    for (int i = threadIdx.x; i < NB; i += ATHR) {
        hp[i] = (unsigned short)lh[i];             // block sees 32768 vals: fits u16
        dp[i] = ldd[i];
    }
    for (int off = 32; off > 0; off >>= 1) bce += __shfl_down(bce, off, 64);
    __shared__ float red[16];
    const int lane = threadIdx.x & 63, wv = threadIdx.x >> 6;
    if (lane == 0) red[wv] = bce;
    __syncthreads();
    if (threadIdx.x == 0) {
        float s = 0.f;
        for (int w = 0; w < 16; w++) s += red[w];
        bce_part[blockIdx.x] = s;
    }
}

// --- Pass B: per batch: merge partials, suffix-scan -> tb, R; S1 = sum of
// bucket-dd above tb (deterministic). Zeroes cnt for pass C. 32 x 1024.
__global__ __launch_bounds__(1024) void select_kernel(
        const unsigned short* __restrict__ hist_part, const float* __restrict__ dsum_part,
        const int* __restrict__ kptr, int* __restrict__ tbR, int* __restrict__ cnt,
        float* __restrict__ S1) {
    __shared__ int   lh[NB];
    __shared__ float ldd[NB];
    __shared__ int   suf[1025];
    __shared__ int   s_tb;
    __shared__ float fred[16];
    const int b = blockIdx.x, t = threadIdx.x;
    if (t == 0) cnt[b] = 0;
    const unsigned short* hp = hist_part + (size_t)b * HPB * NB;
    const float*          dp = dsum_part + (size_t)b * HPB * NB;
    for (int i = t; i < NB; i += 1024) {
        int s = 0; float f = 0.f;
        #pragma unroll
        for (int p = 0; p < HPB; p++) { s += hp[(size_t)p * NB + i]; f += dp[(size_t)p * NB + i]; }
        lh[i] = s; ldd[i] = f;
    }
    __syncthreads();
    const int base = t * 4;
    int c = lh[base] + lh[base + 1] + lh[base + 2] + lh[base + 3];
    suf[t] = c;
    if (t == 0) suf[1024] = 0;
    __syncthreads();
    for (int off = 1; off < 1024; off <<= 1) {
        int v = suf[t] + ((t + off < 1024) ? suf[t + off] : 0);
        __syncthreads();
        suf[t] = v;
        __syncthreads();
    }
    const int K = *kptr;
    {
        int cum = suf[t + 1];      // elements in buckets strictly above this chunk
        #pragma unroll
        for (int i = 3; i >= 0; i--) {
            int hb = lh[base + i];
            if (cum < K && cum + hb >= K) {
                s_tb = base + i;
                tbR[2 * b] = base + i; tbR[2 * b + 1] = K - cum;
            }
            cum += hb;
        }
    }
    __syncthreads();
    const int tb = s_tb;
    float s1p = 0.f;
    for (int i = t; i < NB; i += 1024) if (i > tb) s1p += ldd[i];
    for (int off = 32; off > 0; off >>= 1) s1p += __shfl_down(s1p, off, 64);
    const int lane = t & 63, wv = t >> 6;
    if (lane == 0) fred[wv] = s1p;
    __syncthreads();
    if (t == 0) {
        float s = 0.f;
        for (int w = 0; w < 16; w++) s += fred[w];
        S1[b] = s;
    }
}

// --- Pass C (R6-proven wide shape): collect (value,index) of threshold-bucket
// elements; smap re-read is L3-hot. 1024 blocks x 256 thr.
__global__ __launch_bounds__(256) void collect_kernel(const float* __restrict__ smap,
        const int* __restrict__ tbR, int* __restrict__ cnt,
        float* __restrict__ cval, int* __restrict__ cidx) {
    const int b = blockIdx.x >> 5, cb = blockIdx.x & 31;
    const int tb = tbR[2 * b];
    const int t = cb * 256 + threadIdx.x;          // [0, 8192) group of 32 tokens
    const f4* src = (const f4*)(smap + (size_t)b * NTOK) + (size_t)t * 8;
    const int n0 = t * 32;
    #pragma unroll
    for (int j = 0; j < 8; j++) {
        f4 v = src[j];
        float vv[4] = {v.x, v.y, v.z, v.w};
        #pragma unroll
        for (int s = 0; s < 4; s++) {
            if (bucket_of(vv[s]) == tb) {
                int p = atomicAdd(&cnt[b], 1);
                if (p < CAP) {
                    cval[b * CAP + p] = vv[s];
                    cidx[b * CAP + p] = n0 + 4 * j + s;
                }
            }
        }
    }
}

// --- Pass D: exact rank (value desc, index asc); winners (rank<R) gather their
// (ds,u) pair, recompute dd (same ops as pass A), deterministic S2 reduce.
// corr[b] = S1 + S2. 32 x 256.
__global__ __launch_bounds__(256) void refine_kernel(
        const float* __restrict__ ds, const float* __restrict__ u,
        const float* __restrict__ dsum_part, const int* __restrict__ tbR,
        const int* __restrict__ cnt, const float* __restrict__ cval,
        const int* __restrict__ cidx, const float* __restrict__ S1,
        float* __restrict__ corr) {
    const int b = blockIdx.x, t = threadIdx.x;
    const int R = tbR[2 * b + 1];
    int M = cnt[b];
    const bool ovf = (M > CAP);
    if (M > CAP) M = CAP;
    __shared__ float sv[CAP];
    __shared__ int   si[CAP];
    __shared__ float csel[CAP];
    for (int i = t; i < CAP; i += 256) csel[i] = 0.f;
    for (int i = t; i < M; i += 256) {
        sv[i] = cval[b * CAP + i];
        si[i] = cidx[b * CAP + i];
    }
    __syncthreads();
    if (ovf || R > M || R < 1) {
        // select whole bucket (approximate; never hit: E[M]~64): S2 = ldd[tb]
        if (t == 0) {
            const int tb = tbR[2 * b];
            float s2 = 0.f;
            for (int p = 0; p < HPB; p++)
                s2 += dsum_part[(size_t)(b * HPB + p) * NB + tb];
            corr[b] = S1[b] + s2;
        }
        return;
    }
    for (int i = t; i < M; i += 256) {
        float vi = sv[i]; int ii = si[i];
        int r = 0;
        for (int j = 0; j < M; j++) {
            float vj = sv[j];
            r += (vj > vi) || (vj == vi && si[j] < ii);
        }
        if (r < R) {
            float2 dpair = ((const float2*)ds)[(size_t)b * NTOK + ii];
            float2 upair = ((const float2*)u)[(size_t)b * NTOK + ii];
            float g0 = -__logf(-__logf(upair.x));
            float g1 = -__logf(-__logf(upair.y));
            csel[i] = (dpair.x + g0) - (dpair.y + g1);   // dd, same ops as pass A
        }
    }
    __syncthreads();
    // deterministic reduce over csel[0..CAP)
    float s2p = 0.f;
    #pragma unroll
    for (int k = 0; k < CAP / 256; k++) s2p += csel[t + k * 256];
    for (int off = 32; off > 0; off >>= 1) s2p += __shfl_down(s2p, off, 64);
    __shared__ float fred[4];
    const int lane = t & 63, wv = t >> 6;
    if (lane == 0) fred[wv] = s2p;
    __syncthreads();
    if (t == 0) corr[b] = S1[b] + (fred[0] + fred[1] + fred[2] + fred[3]);
}

// --- Pass E: out = sum(bce_part) - sum(corr) ---
__global__ __launch_bounds__(256) void final_kernel(const float* __restrict__ bce_part,
                                                    const float* __restrict__ corr,
                                                    float* __restrict__ out) {
    const int t = threadIdx.x;
    float a = bce_part[t];                 // exactly ABLK==256 partials
    for (int off = 32; off > 0; off >>= 1) a += __shfl_down(a, off, 64);
    __shared__ float red[4];
    const int lane = t & 63, wv = t >> 6;
    if (lane == 0) red[wv] = a;
    __syncthreads();
    if (t == 0) {
        float s = red[0] + red[1] + red[2] + red[3];
        float cc = 0.f;
        for (int i = 0; i < BATCH; i++) cc += corr[i];
        out[0] = s - cc;
    }
}

extern "C" void kernel_launch(void* const* d_in, const int* in_sizes, int n_in,
                              void* d_out, int out_size, void* d_ws, size_t ws_size,
                              hipStream_t stream) {
    const float* ds   = (const float*)d_in[0];   // [B, N, 2]
    const float* smap = (const float*)d_in[1];   // [B, 1, H, W] == [B, N]
    const float* u    = (const float*)d_in[2];   // [B, N, 2]
    const int*   kptr = (const int*)d_in[3];     // scalar K

    // workspace (~7.3 MB): dsum_part f32[256*4096]=4MB | hist_part u16[256*4096]=2MB
    // | bce_part[256] | tbR[64] | cnt[32] | S1[32] | corr[32]
    // | cval f32[32*4096]=512KB | cidx int[32*4096]=512KB
    float*          dsum_part = (float*)d_ws;
    unsigned short* hist_part = (unsigned short*)(dsum_part + (size_t)ABLK * NB);
    float* bce_part = (float*)(hist_part + (size_t)ABLK * NB);
    int*   tbR      = (int*)(bce_part + ABLK);
    int*   cnt      = tbR + 2 * BATCH;
    float* S1       = (float*)(cnt + BATCH);
    float* corr     = S1 + BATCH;
    float* cval     = corr + BATCH;
    int*   cidx     = (int*)(cval + (size_t)BATCH * CAP);

    fused_kernel<<<ABLK, ATHR, 0, stream>>>(ds, u, smap, hist_part, dsum_part, bce_part);
    select_kernel<<<BATCH, 1024, 0, stream>>>(hist_part, dsum_part, kptr, tbR, cnt, S1);
    collect_kernel<<<1024, 256, 0, stream>>>(smap, tbR, cnt, cval, cidx);
    refine_kernel<<<BATCH, 256, 0, stream>>>(ds, u, dsum_part, tbR, cnt, cval, cidx, S1, corr);
    final_kernel<<<1, 256, 0, stream>>>(bce_part, corr, (float*)d_out);
}

// Round 8
// 205.042 us; speedup vs baseline: 1.0304x; 1.0304x over previous
//
#include <hip/hip_runtime.h>

#define NB    4096      // histogram buckets over [0,1)
#define CAP   4096      // per-batch candidate capacity (expected ~64 in threshold bucket)
#define BATCH 32
#define NTOK  262144    // 512*512
#define HPB   8         // hist blocks per batch
#define HBLK  (BATCH * HPB)   // 256
#define NWRD  (NTOK / 32)     // 8192 mask words per batch
#define LOSS_BLOCKS 4096      // 8 tokens/thread, 256 thr (R3-proven 3.26 TB/s shape)

typedef float f4 __attribute__((ext_vector_type(4)));

__device__ __forceinline__ int bucket_of(float v) {
    int b = (int)(v * (float)NB);
    return b > NB - 1 ? NB - 1 : b;
}

// --- Pass 1: per-block partial histograms (R3-proven). 256 blocks x 1024 thr.
__global__ __launch_bounds__(1024) void hist_kernel(const float* __restrict__ smap,
                                                    unsigned short* __restrict__ hist_part) {
    __shared__ int lh[NB];
    for (int i = threadIdx.x; i < NB; i += 1024) lh[i] = 0;
    __syncthreads();
    const int b = blockIdx.x >> 3, cb = blockIdx.x & 7;
    const f4* src = (const f4*)(smap + (size_t)b * NTOK + (size_t)cb * (NTOK / HPB));
    for (int k = 0; k < 8; k++) {
        f4 v = src[threadIdx.x + k * 1024];
        atomicAdd(&lh[bucket_of(v.x)], 1);
        atomicAdd(&lh[bucket_of(v.y)], 1);
        atomicAdd(&lh[bucket_of(v.z)], 1);
        atomicAdd(&lh[bucket_of(v.w)], 1);
    }
    __syncthreads();
    unsigned short* hp = hist_part + (size_t)blockIdx.x * NB;
    for (int i = threadIdx.x; i < NB; i += 1024)
        hp[i] = (unsigned short)lh[i];            // block sees 32768 vals: fits u16
}

// --- Pass 2: merge partials, suffix-scan, threshold bucket tb + residual rank R.
// Also zeroes cnt (runs before collect -> no memset dispatch).
__global__ __launch_bounds__(1024) void select_kernel(
        const unsigned short* __restrict__ hist_part, const int* __restrict__ kptr,
        int* __restrict__ tbR, int* __restrict__ cnt) {
    __shared__ int lh[NB];
    __shared__ int suf[1025];
    const int b = blockIdx.x, t = threadIdx.x;
    if (t == 0) cnt[b] = 0;
    const unsigned short* hp = hist_part + (size_t)b * HPB * NB;
    for (int i = t; i < NB; i += 1024) {
        int s = 0;
        #pragma unroll
        for (int p = 0; p < HPB; p++) s += hp[(size_t)p * NB + i];
        lh[i] = s;
    }
    __syncthreads();
    const int base = t * 4;
    int c = lh[base] + lh[base + 1] + lh[base + 2] + lh[base + 3];
    suf[t] = c;
    if (t == 0) suf[1024] = 0;
    __syncthreads();
    for (int off = 1; off < 1024; off <<= 1) {
        int v = suf[t] + ((t + off < 1024) ? suf[t + off] : 0);
        __syncthreads();
        suf[t] = v;
        __syncthreads();
    }
    const int K = *kptr;
    int cum = suf[t + 1];          // elements in buckets strictly above this chunk
    #pragma unroll
    for (int i = 3; i >= 0; i--) {
        int hb = lh[base + i];
        if (cum < K && cum + hb >= K) { tbR[2 * b] = base + i; tbR[2 * b + 1] = K - cum; }
        cum += hb;
    }
}

// --- Pass 3: build 1-bit selection mask (bid > tb) and collect tb-bucket candidates.
// 1024 blocks x 256 thr; each thread owns 32 consecutive tokens -> one u32 word,
// NO atomics on the mask. smap read is L3-hot after pass 1. (R6-proven)
__global__ __launch_bounds__(256) void maskcollect_kernel(const float* __restrict__ smap,
        const int* __restrict__ tbR, unsigned* __restrict__ mask,
        int* __restrict__ cnt, float* __restrict__ cval, int* __restrict__ cidx) {
    const int b = blockIdx.x >> 5, cb = blockIdx.x & 31;
    const int tb = tbR[2 * b];
    const int t = cb * 256 + threadIdx.x;          // [0, 8192) word index in batch
    const f4* src = (const f4*)(smap + (size_t)b * NTOK) + (size_t)t * 8;
    const int n0 = t * 32;                          // first token of this word
    unsigned w = 0;
    #pragma unroll
    for (int j = 0; j < 8; j++) {
        f4 v = src[j];
        float vv[4] = {v.x, v.y, v.z, v.w};
        #pragma unroll
        for (int s = 0; s < 4; s++) {
            int bk = bucket_of(vv[s]);
            if (bk > tb) {
                w |= 1u << (4 * j + s);
            } else if (bk == tb) {
                int p = atomicAdd(&cnt[b], 1);
                if (p < CAP) {
                    cval[b * CAP + p] = vv[s];
                    cidx[b * CAP + p] = n0 + 4 * j + s;
                }
            }
        }
    }
    mask[(size_t)b * NWRD + t] = w;
}

// --- Pass 4: exact rank under (value desc, index asc); winners (rank < R) set
// their mask bit. ~64 atomicOr per batch. (R6-proven)
__global__ __launch_bounds__(256) void refine_kernel(const int* __restrict__ tbR,
        const int* __restrict__ cnt, const float* __restrict__ cval,
        const int* __restrict__ cidx, unsigned* __restrict__ mask) {
    const int b = blockIdx.x;
    const int R = tbR[2 * b + 1];
    int M = cnt[b];
    if (M > CAP) M = CAP;   // overflow: approximate among stored (never hit: E[M]~64)
    __shared__ float sv[CAP];
    __shared__ int   si[CAP];
    for (int i = threadIdx.x; i < M; i += 256) {
        sv[i] = cval[b * CAP + i];
        si[i] = cidx[b * CAP + i];
    }
    __syncthreads();
    for (int i = threadIdx.x; i < M; i += 256) {
        float vi = sv[i]; int ii = si[i];
        int r = 0;
        for (int j = 0; j < M; j++) {
            float vj = sv[j];
            r += (vj > vi) || (vj == vi && si[j] < ii);
        }
        if (r < R)
            atomicOr(&mask[(size_t)b * NWRD + (ii >> 5)], 1u << (ii & 31));
    }
}

__device__ __forceinline__ float token_loss(float d0, float d1, float u0, float u1,
                                            bool sel) {
    float g0 = -__logf(-__logf(u0));
    float g1 = -__logf(-__logf(u1));
    float dd = (d0 + g0) - (d1 + g1);
    float l  = __logf(1.f + __expf(-fabsf(dd)));
    float lp0 = (dd >= 0.f) ? -l      : dd - l;
    float lp1 = (dd >= 0.f) ? -l - dd : -l;
    lp0 = fmaxf(lp0, -100.f); lp1 = fmaxf(lp1, -100.f);
    return sel ? -lp0 : -lp1;
}

// --- Pass 5: fused loss. R3's 8-token/thread shape (best measured: 3.26 TB/s)
// x R6's mask selection (129 MB reads). 4096 blocks x 256 thr.
// Per thread: 4x ds float4 + 4x u float4 + 1 mask dword (4 threads/word).
__global__ __launch_bounds__(256) void loss_kernel(const float* __restrict__ ds,
        const float* __restrict__ u, const unsigned* __restrict__ mask,
        float* __restrict__ partials) {
    const int b = blockIdx.x >> 7;                          // 128 blocks per batch
    const int r = ((blockIdx.x & 127) << 8) | threadIdx.x;  // [0, 32768): 8-token group
    const f4* ds4 = (const f4*)(ds + (size_t)b * NTOK * 2) + 4 * (size_t)r;
    const f4* u4  = (const f4*)(u  + (size_t)b * NTOK * 2) + 4 * (size_t)r;

    // issue all 9 loads up-front (R3 pattern + mask word)
    f4 d0 = ds4[0], d1 = ds4[1], d2 = ds4[2], d3 = ds4[3];
    f4 w0 = u4[0],  w1 = u4[1],  w2 = u4[2],  w3 = u4[3];
    unsigned w = mask[(size_t)b * NWRD + (r >> 2)];   // 4 threads share a word
    const int sh = (r & 3) * 8;                        // this thread's 8 bits

    float acc = token_loss(d0.x, d0.y, w0.x, w0.y, (w >> (sh + 0)) & 1)
              + token_loss(d0.z, d0.w, w0.z, w0.w, (w >> (sh + 1)) & 1)
              + token_loss(d1.x, d1.y, w1.x, w1.y, (w >> (sh + 2)) & 1)
              + token_loss(d1.z, d1.w, w1.z, w1.w, (w >> (sh + 3)) & 1)
              + token_loss(d2.x, d2.y, w2.x, w2.y, (w >> (sh + 4)) & 1)
              + token_loss(d2.z, d2.w, w2.z, w2.w, (w >> (sh + 5)) & 1)
              + token_loss(d3.x, d3.y, w3.x, w3.y, (w >> (sh + 6)) & 1)
              + token_loss(d3.z, d3.w, w3.z, w3.w, (w >> (sh + 7)) & 1);

    for (int off = 32; off > 0; off >>= 1) acc += __shfl_down(acc, off, 64);
    __shared__ float red[4];
    const int lane = threadIdx.x & 63, wv = threadIdx.x >> 6;
    if (lane == 0) red[wv] = acc;
    __syncthreads();
    if (threadIdx.x == 0)
        partials[blockIdx.x] = red[0] + red[1] + red[2] + red[3];
}

// --- Pass 6: reduce LOSS_BLOCKS partials into out[0] ---
__global__ __launch_bounds__(1024) void reduce_kernel(const float* __restrict__ partials,
                                                      float* __restrict__ out) {
    float acc = 0.f;
    for (int i = threadIdx.x; i < LOSS_BLOCKS; i += 1024) acc += partials[i];
    for (int off = 32; off > 0; off >>= 1) acc += __shfl_down(acc, off, 64);
    __shared__ float red[16];
    const int lane = threadIdx.x & 63, wv = threadIdx.x >> 6;
    if (lane == 0) red[wv] = acc;
    __syncthreads();
    if (threadIdx.x == 0) {
        float s = 0.f;
        for (int w = 0; w < 16; w++) s += red[w];
        out[0] = s;
    }
}

extern "C" void kernel_launch(void* const* d_in, const int* in_sizes, int n_in,
                              void* d_out, int out_size, void* d_ws, size_t ws_size,
                              hipStream_t stream) {
    const float* ds   = (const float*)d_in[0];   // [B, N, 2]
    const float* smap = (const float*)d_in[1];   // [B, 1, H, W] == [B, N]
    const float* u    = (const float*)d_in[2];   // [B, N, 2]
    const int*   kptr = (const int*)d_in[3];     // scalar K

    // workspace (~4.2 MB): hist_part u16[256*4096]=2MB | mask u32[32*8192]=1MB
    // | tbR[64] | cnt[32] | cval[32*4096]=512KB | cidx[32*4096]=512KB | partials[4096]
    unsigned short* hist_part = (unsigned short*)d_ws;
    unsigned* mask  = (unsigned*)(hist_part + (size_t)HBLK * NB);
    int*   tbR      = (int*)(mask + (size_t)BATCH * NWRD);
    int*   cnt      = tbR + 2 * BATCH;
    float* cval     = (float*)(cnt + BATCH);
    int*   cidx     = (int*)(cval + (size_t)BATCH * CAP);
    float* partials = (float*)(cidx + (size_t)BATCH * CAP);

    hist_kernel<<<HBLK, 1024, 0, stream>>>(smap, hist_part);
    select_kernel<<<BATCH, 1024, 0, stream>>>(hist_part, kptr, tbR, cnt);
    maskcollect_kernel<<<1024, 256, 0, stream>>>(smap, tbR, mask, cnt, cval, cidx);
    refine_kernel<<<BATCH, 256, 0, stream>>>(tbR, cnt, cval, cidx, mask);
    loss_kernel<<<LOSS_BLOCKS, 256, 0, stream>>>(ds, u, mask, partials);
    reduce_kernel<<<1, 1024, 0, stream>>>(partials, (float*)d_out);
}